// Round 5
// baseline (93.045 us; speedup 1.0000x reference)
//
#include <hip/hip_runtime.h>
#include <stdint.h>

#define N 4096
#define BM 128
#define BN 128
#define BK 64
#define TILES 32      // N/BM
#define NCHUNKS 1000  // upper-tile K-chunks (bi>=8 split into ceil((bi+1)/8))
#define NZERO 28      // lower tiles with bi<8 (rows not covered by prep C-zeroing)
#define NITEMS (NCHUNKS + NZERO)
#define NWORKERS 512  // 2 blocks/CU at 64KB LDS
#define CHUNK_STEPS 16

typedef __attribute__((ext_vector_type(8))) short s16x8;
typedef __attribute__((ext_vector_type(4))) float f32x4;

// round-to-nearest-even fp32 -> bf16
__device__ __forceinline__ unsigned short f2bf(float f) {
  union { float f; unsigned int u; } c; c.f = f;
  unsigned int u = c.u;
  unsigned int r = (u + 0x7fffu + ((u >> 16) & 1u)) >> 16;
  return (unsigned short)r;
}

__device__ __forceinline__ void gld16(const void* g, void* l) {
  __builtin_amdgcn_global_load_lds(
      (const __attribute__((address_space(1))) unsigned int*)g,
      (__attribute__((address_space(3))) unsigned int*)l,
      16, 0, 0);
}

// Fused prepass: A -> tril-masked bf16, B -> triu-masked bf16 transposed,
// C rows [1024,4096) zeroed (atomicAdd targets for split-K tiles bi>=8).
// Block 0 also resets the work counter.
__global__ void prep(const float* __restrict__ A, const float* __restrict__ B,
                     unsigned short* __restrict__ Abf, unsigned short* __restrict__ Bt,
                     float* __restrict__ C, int* __restrict__ cnt) {
  int bid = blockIdx.x;
  int t = threadIdx.x;
  if (bid == 0 && t == 0) *cnt = 0;   // prep completes before trigemm starts (stream order)
  if (bid < 8192) {
    // ---- A path: one block = half a row (2048 elems), 8 elems/thread ----
    long base = (long)bid * 2048 + (long)t * 8;
    int row = (int)(base >> 12);
    int k0 = (int)(base & 4095);
    int bound = ((row >> 7) + 1) << 7;       // first k trigemm never reads
    if (k0 >= bound) return;
    if (k0 > row) {
      uint4 z = make_uint4(0u, 0u, 0u, 0u);
      *reinterpret_cast<uint4*>(Abf + base) = z;
      return;
    }
    const float4* src = reinterpret_cast<const float4*>(A + base);
    float4 v0 = src[0], v1 = src[1];
    float vs[8] = {v0.x, v0.y, v0.z, v0.w, v1.x, v1.y, v1.z, v1.w};
    unsigned int w[4];
#pragma unroll
    for (int i = 0; i < 4; i++) {
      unsigned int lo = (k0 + 2*i     <= row) ? f2bf(vs[2*i])     : 0u;
      unsigned int hi = (k0 + 2*i + 1 <= row) ? f2bf(vs[2*i + 1]) : 0u;
      w[i] = lo | (hi << 16);
    }
    uint4 o; o.x = w[0]; o.y = w[1]; o.z = w[2]; o.w = w[3];
    *reinterpret_cast<uint4*>(Abf + base) = o;
  } else if (bid < 12288) {
    // ---- B path: 64x64 tile transpose with triu mask ----
    int b2 = bid - 8192;
    int k0 = (b2 & 63) * 64;
    int c0 = (b2 >> 6) * 64;
    int cj = c0 >> 7;
    if (k0 >= ((cj + 1) << 7)) return;        // never read by trigemm
    if (k0 > c0 + 63) {
      ushort4 z = make_ushort4(0, 0, 0, 0);
#pragma unroll
      for (int p = 0; p < 4; p++) {
        int cl = p * 16 + (t >> 4);
        int kl = (t & 15) * 4;
        *reinterpret_cast<ushort4*>(Bt + (long)(c0 + cl) * N + k0 + kl) = z;
      }
      return;
    }
    __shared__ unsigned short lds[64][72];    // +8 pad breaks transpose conflicts
#pragma unroll
    for (int p = 0; p < 4; p++) {
      int kl = p * 16 + (t >> 4);
      int cl = (t & 15) * 4;
      float4 v = *reinterpret_cast<const float4*>(B + (long)(k0 + kl) * N + c0 + cl);
      float vs[4] = {v.x, v.y, v.z, v.w};
#pragma unroll
      for (int i = 0; i < 4; i++)
        lds[kl][cl + i] = (k0 + kl <= c0 + cl + i) ? f2bf(vs[i]) : (unsigned short)0;
    }
    __syncthreads();
#pragma unroll
    for (int p = 0; p < 4; p++) {
      int cl = p * 16 + (t >> 4);
      int kl = (t & 15) * 4;
      ushort4 o;
      o.x = lds[kl + 0][cl]; o.y = lds[kl + 1][cl];
      o.z = lds[kl + 2][cl]; o.w = lds[kl + 3][cl];
      *reinterpret_cast<ushort4*>(Bt + (long)(c0 + cl) * N + k0 + kl) = o;
    }
  } else {
    // ---- C-zero path: rows [1024,4096), 16B per thread ----
    long idx = (long)(bid - 12288) * 256 + t;
    float4 z = make_float4(0.f, 0.f, 0.f, 0.f);
    *reinterpret_cast<float4*>(C + (long)1024 * N + idx * 4) = z;
  }
}

// Triangular bf16 MFMA GEMM: C = triu(Abf @ Bt^T), split-K.
// 512 persistent workers drain an atomic LPT (heavy-first) queue of K-chunks
// (<=16 k64-steps each). bi>=8 chunks atomicAdd partials into prep-zeroed C;
// bi<8 tiles are single-chunk plain stores.
__global__ __launch_bounds__(256) void trigemm(
    const unsigned short* __restrict__ Abf,
    const unsigned short* __restrict__ Bt,
    float* __restrict__ C, int* __restrict__ cnt) {
  __shared__ unsigned short lA[2][BM * BK];  // 2 x 16KB, 16B-chunk XOR swizzled
  __shared__ unsigned short lB[2][BN * BK];
  __shared__ int sh;

  int t = threadIdx.x;
  int lane = t & 63, wave = t >> 6;

  // staging addressing: 256 thr x 16B = 4KB = 32 rows x 128B per issue
  int r8 = wave * 8 + (lane >> 3);
  int kc = lane & 7;
  int kcs = kc ^ (r8 & 7);            // inverse-swizzled source chunk
  int l15 = lane & 15, l4 = lane >> 4;
  int wr = wave >> 1, wc = wave & 1;

  for (;;) {
    if (t == 0) sh = atomicAdd(cnt, 1);
    __syncthreads();
    int rank = sh;
    __syncthreads();          // protect sh before next iteration's write
    if (rank >= NITEMS) return;

    // rank -> (bi, bj, K-chunk): heavy-first (bi descending), chunks within tile
    int bi, bj, kt0 = 0;
    bool upper;
    if (rank < NCHUNKS) {
      upper = true;
      int b_i = TILES - 1, acc = 0;
      for (;;) {
        int ch = (b_i + 8) >> 3;                 // ceil((bi+1)/8) chunks per tile
        int cnt_bi = (TILES - b_i) * ch;
        if (rank < acc + cnt_bi) {
          int u = rank - acc;
          int q = u / ch;
          bj = b_i + q;
          kt0 = (u - q * ch) * CHUNK_STEPS;
          break;
        }
        acc += cnt_bi; --b_i;
      }
      bi = b_i;
    } else {
      upper = false;
      int u = rank - NCHUNKS;
      int r = 1, acc = 0;
      while (u >= acc + r) { acc += r; ++r; }
      bi = r; bj = u - acc;                      // bi in 1..7 (rows <1024, not prep-zeroed)
    }

    if (!upper) {
      float4 z = make_float4(0.f, 0.f, 0.f, 0.f);
#pragma unroll
      for (int i = 0; i < 16; i++) {
        int pos = i * 256 + t;
        int row = pos >> 5, c4 = pos & 31;
        *reinterpret_cast<float4*>(C + (long)(bi * BM + row) * N + bj * BN + c4 * 4) = z;
      }
      continue;
    }

    int row0 = bi * BM, col0 = bj * BN;
    int nk = (bi + 1) * 2;                       // total k64-steps for this tile
    int kt1 = nk < kt0 + CHUNK_STEPS ? nk : kt0 + CHUNK_STEPS;
    bool use_atomic = bi >= 8;

    const unsigned short* gA = Abf + (long)(row0 + r8) * N + kcs * 8;
    const unsigned short* gB = Bt  + (long)(col0 + r8) * N + kcs * 8;
    unsigned short* sA = &lA[0][0] + r8 * BK + kc * 8;
    unsigned short* sB = &lB[0][0] + r8 * BK + kc * 8;

    f32x4 acc[4][4];
#pragma unroll
    for (int m = 0; m < 4; m++)
#pragma unroll
      for (int n = 0; n < 4; n++)
        acc[m][n] = (f32x4){0.f, 0.f, 0.f, 0.f};

    // prologue: stage k-tile kt0 into buffer 0 (8 loads)
#pragma unroll
    for (int i = 0; i < 4; i++) {
      gld16(gA + (long)i * 32 * N + (long)kt0 * BK, sA + i * 32 * BK);
      gld16(gB + (long)i * 32 * N + (long)kt0 * BK, sB + i * 32 * BK);
    }

    int cur = 0;
    for (int kt = kt0; kt < kt1; ++kt) {
      if (kt + 1 < kt1) {
        long kof = (long)(kt + 1) * BK;
        int nb = cur ^ 1;
#pragma unroll
        for (int i = 0; i < 4; i++) {
          gld16(gA + (long)i * 32 * N + kof, sA + nb * (BM * BK) + i * 32 * BK);
          gld16(gB + (long)i * 32 * N + kof, sB + nb * (BN * BK) + i * 32 * BK);
        }
        asm volatile("s_waitcnt vmcnt(8)" ::: "memory");  // current buffer's 8 loads done
      } else {
        asm volatile("s_waitcnt vmcnt(0)" ::: "memory");
      }
      __builtin_amdgcn_s_barrier();

      const unsigned short* bA = &lA[0][0] + cur * (BM * BK);
      const unsigned short* bB = &lB[0][0] + cur * (BN * BK);
#pragma unroll
      for (int kk = 0; kk < 2; kk++) {
        s16x8 af[4], bf[4];
#pragma unroll
        for (int m = 0; m < 4; m++) {
          int row = wr * 64 + m * 16 + l15;
          int lin = row * BK + kk * 32 + l4 * 8;
          int addr = lin ^ ((row & 7) << 3);     // zero-conflict XOR swizzle
          af[m] = *reinterpret_cast<const s16x8*>(&bA[addr]);
        }
#pragma unroll
        for (int n = 0; n < 4; n++) {
          int col = wc * 64 + n * 16 + l15;
          int lin = col * BK + kk * 32 + l4 * 8;
          int addr = lin ^ ((col & 7) << 3);
          bf[n] = *reinterpret_cast<const s16x8*>(&bB[addr]);
        }
#pragma unroll
        for (int m = 0; m < 4; m++)
#pragma unroll
          for (int n = 0; n < 4; n++)
            acc[m][n] = __builtin_amdgcn_mfma_f32_16x16x32_bf16(af[m], bf[n], acc[m][n], 0, 0, 0);
      }
      __builtin_amdgcn_s_barrier();
      cur ^= 1;
    }

    // epilogue: C/D layout col=lane&15, row=(lane>>4)*4+reg (m89-verified)
    bool diag = (bi == bj);
#pragma unroll
    for (int m = 0; m < 4; m++) {
      int rowb = row0 + wr * 64 + m * 16 + l4 * 4;
#pragma unroll
      for (int n = 0; n < 4; n++) {
        int col = col0 + wc * 64 + n * 16 + l15;
#pragma unroll
        for (int r = 0; r < 4; r++) {
          int row = rowb + r;
          float v = acc[m][n][r];
          if (use_atomic) {
            if (!(diag && row > col)) atomicAdd(&C[(long)row * N + col], v);
          } else {
            if (diag && row > col) v = 0.f;
            C[(long)row * N + col] = v;
          }
        }
      }
    }
  }
}

extern "C" void kernel_launch(void* const* d_in, const int* in_sizes, int n_in,
                              void* d_out, int out_size, void* d_ws, size_t ws_size,
                              hipStream_t stream) {
  const float* A = (const float*)d_in[0];
  const float* B = (const float*)d_in[1];
  float* C = (float*)d_out;
  // workspace: Abf (32MB) + Bt (32MB), both bf16 4096x4096
  unsigned short* Abf = (unsigned short*)d_ws;
  unsigned short* Bt = Abf + (size_t)N * N;
  // work-queue counter hidden in a hole of Bt that trigemm never reads and prep never
  // writes: col-tile 0 only uses k<128; pick col=0, k=2048.
  int* cnt = (int*)(Bt + 2048);

  prep<<<dim3(8192 + 4096 + 12288), dim3(256), 0, stream>>>(A, B, Abf, Bt, C, cnt);
  trigemm<<<dim3(NWORKERS), dim3(256), 0, stream>>>(Abf, Bt, C, cnt);
}